// Round 6
// baseline (623.789 us; speedup 1.0000x reference)
//
#include <hip/hip_runtime.h>
#include <hip/hip_bf16.h>

// EdgeWeightFromDistance: out[e] = relu(relu([x[src], y[dst], dist] @ W1 + b1) @ W2 + b2)
// E = 1e6, NODE_DIM = 64, HIDDEN = 128.
// R6: duty-cycle bound (all pipes 15-55%, waves alternate ~700cyc gather-wait /
//     ~600cyc compute at only 16 waves/CU). VGPR=64 = exactly the 8-waves/SIMD
//     threshold; the occupancy cap was 256-thread blocks each holding a private
//     34.8 KB Wt (LDS allows 4 blocks/CU). -> 512-thread blocks (8 waves share
//     one Wt), __launch_bounds__(512,8), grid 1024 = 32 waves/CU (2x occupancy).

constexpr int NDIM  = 64;
constexpr int HID   = 128;
constexpr int KPAD  = 136;   // bf16 elems per Wt row: 128 data + w1r + b1 + 6 zeros; 272 B

typedef __attribute__((ext_vector_type(8))) short  short8;
typedef __attribute__((ext_vector_type(4))) int    int4v;
typedef __attribute__((ext_vector_type(4))) float  floatx4;

__device__ __forceinline__ short f2bf(float f) {
    union { __hip_bfloat16 h; short s; } cv;
    cv.h = __float2bfloat16(f);
    return cv.s;
}

__device__ __forceinline__ int pack2(float a, float b) {
    union { __hip_bfloat162 h; int u; } cv;
    cv.h = __float22bfloat162_rn(float2{a, b});
    return cv.u;
}

__device__ __forceinline__ short8 make_afrag_f32(const float* rp) {
    const floatx4 f0 = *reinterpret_cast<const floatx4*>(rp);
    const floatx4 f1 = *reinterpret_cast<const floatx4*>(rp + 4);
    union { int4v i; short8 s8; } cv;
    cv.i.x = pack2(f0.x, f0.y);
    cv.i.y = pack2(f0.z, f0.w);
    cv.i.z = pack2(f1.x, f1.y);
    cv.i.w = pack2(f1.z, f1.w);
    return cv.s8;
}

// ---- streaming fp32 -> bf16 convert of x,y + per-edge bf16 dist into workspace ----
__global__ __launch_bounds__(256) void cvt_kernel(
    const float* __restrict__ xin, const float* __restrict__ yin,
    const int*  __restrict__ ei,  const float* __restrict__ px,
    const float* __restrict__ py,
    short* __restrict__ xb, short* __restrict__ yb, short* __restrict__ db,
    int nfl, int E)
{
    const int stride = gridDim.x * blockDim.x;
    const int gid = blockIdx.x * blockDim.x + threadIdx.x;
    const int n8 = nfl >> 3;
    for (int i = gid; i < n8; i += stride) {
        {
            const floatx4 f0 = *reinterpret_cast<const floatx4*>(xin + i * 8);
            const floatx4 f1 = *reinterpret_cast<const floatx4*>(xin + i * 8 + 4);
            union { int4v v; short8 s; } c;
            c.v.x = pack2(f0.x, f0.y); c.v.y = pack2(f0.z, f0.w);
            c.v.z = pack2(f1.x, f1.y); c.v.w = pack2(f1.z, f1.w);
            *reinterpret_cast<short8*>(xb + i * 8) = c.s;
        }
        {
            const floatx4 f0 = *reinterpret_cast<const floatx4*>(yin + i * 8);
            const floatx4 f1 = *reinterpret_cast<const floatx4*>(yin + i * 8 + 4);
            union { int4v v; short8 s; } c;
            c.v.x = pack2(f0.x, f0.y); c.v.y = pack2(f0.z, f0.w);
            c.v.z = pack2(f1.x, f1.y); c.v.w = pack2(f1.z, f1.w);
            *reinterpret_cast<short8*>(yb + i * 8) = c.s;
        }
    }
    // per-edge distance (pos arrays are 2.4 MB total -> L2-resident gathers)
    for (int e = gid; e < E; e += stride) {
        const int s = ei[e];
        const int d = ei[E + e];
        const float dx = px[s * 3 + 0] - py[d * 3 + 0];
        const float dy = px[s * 3 + 1] - py[d * 3 + 1];
        const float dz = px[s * 3 + 2] - py[d * 3 + 2];
        db[e] = f2bf(sqrtf(dx * dx + dy * dy + dz * dz));
    }
}

template <bool BF16GATHER>
__global__ __launch_bounds__(512, 8) void edge_mlp_kernel(
    const float* __restrict__ x, const float* __restrict__ y,
    const short* __restrict__ xb, const short* __restrict__ yb,
    const short* __restrict__ db,
    const int*  __restrict__ ei, const float* __restrict__ px,
    const float* __restrict__ py, const float* __restrict__ W1,
    const float* __restrict__ b1, const float* __restrict__ W2,
    const float* __restrict__ b2, float* __restrict__ out, int E)
{
    __shared__ __align__(16) short Wt[HID * KPAD];   // W1^T [n][k] in bf16 (+ fold rows)

    const int tid = threadIdx.x;

    // ---- stage W1[0:128][0:128] transposed into LDS (512 threads) ----
    for (int base = 0; base < HID * HID; base += 512 * 8) {
        float f[8];
#pragma unroll
        for (int u = 0; u < 8; ++u) f[u] = W1[base + u * 512 + tid];
#pragma unroll
        for (int u = 0; u < 8; ++u) {
            int i = base + u * 512 + tid;
            Wt[(i & 127) * KPAD + (i >> 7)] = f2bf(f[u]);
        }
    }
    // fold rows: k=128 -> w1r (dist coeff), k=129 -> b1, k=130..135 -> 0
    if (tid < HID) {
        const int n = tid;
        Wt[n * KPAD + 128] = f2bf(W1[128 * HID + n]);
        Wt[n * KPAD + 129] = f2bf(b1[n]);
#pragma unroll
        for (int j = 130; j < 136; ++j) Wt[n * KPAD + j] = 0;
    }
    __syncthreads();

    const int lane = tid & 63;
    const int wave = tid >> 6;          // 0..7
    const int quad = lane >> 4;
    const int lm   = lane & 15;   // A-frag row m; B-frag/C-D col n (within tile)

    float w2v[8];
#pragma unroll
    for (int t = 0; t < 8; ++t) w2v[t] = W2[t * 16 + lm];
    const float b2s = b2[0];

    const int* __restrict__ srcp = ei;
    const int* __restrict__ dstp = ei + E;

    const int sel5 = (quad == 0) ? 128 : 0;   // fold-step k-offset

    const int ntiles = (E + 255) / 256;       // 256 edges per block-iter, 32 per wave
    int tile = blockIdx.x;
    if (tile >= ntiles) return;

    // ---- prefetch first tile's indices (+ dist for quad 0) ----
    int s0, d0, s1, d1;
    short dd0 = 0, dd1 = 0;
    float fd0 = 0.f, fd1 = 0.f;   // fallback-path dist
    {
        const int mb = tile * 256 + wave * 32;
        const int m0 = min(mb + lm, E - 1);
        const int m1 = min(mb + 16 + lm, E - 1);
        s0 = srcp[m0]; d0 = dstp[m0]; s1 = srcp[m1]; d1 = dstp[m1];
        if (BF16GATHER) {
            if (quad == 0) { dd0 = db[m0]; dd1 = db[m1]; }
        }
    }

    for (; tile < ntiles; tile += gridDim.x) {
        // ---- kick off next tile's idx/dist loads (no deps on current work) ----
        const int nt = tile + gridDim.x;
        const int qt = (nt < ntiles) ? nt : tile;
        const int qmb = qt * 256 + wave * 32;
        const int qm0 = min(qmb + lm, E - 1);
        const int qm1 = min(qmb + 16 + lm, E - 1);
        const int ns0 = srcp[qm0], nd0 = dstp[qm0];
        const int ns1 = srcp[qm1], nd1 = dstp[qm1];
        short ndd0 = 0, ndd1 = 0;
        if (BF16GATHER) {
            if (quad == 0) { ndd0 = db[qm0]; ndd1 = db[qm1]; }
        }

        const int mb = tile * 256 + wave * 32;
        const int src0 = s0, dst0 = d0, src1 = s1, dst1 = d1;

        if (!BF16GATHER) {
            const float dx0 = px[src0 * 3 + 0] - py[dst0 * 3 + 0];
            const float dy0 = px[src0 * 3 + 1] - py[dst0 * 3 + 1];
            const float dz0 = px[src0 * 3 + 2] - py[dst0 * 3 + 2];
            fd0 = sqrtf(dx0 * dx0 + dy0 * dy0 + dz0 * dz0);
            const float dx1 = px[src1 * 3 + 0] - py[dst1 * 3 + 0];
            const float dy1 = px[src1 * 3 + 1] - py[dst1 * 3 + 1];
            const float dz1 = px[src1 * 3 + 2] - py[dst1 * 3 + 2];
            fd1 = sqrtf(dx1 * dx1 + dy1 * dy1 + dz1 * dz1);
        }

        // ---- A fragments: row m, k = s*32 + quad*8 + j ----
        short8 fa[4], fb[4];
#pragma unroll
        for (int s = 0; s < 4; ++s) {
            const int kk = s * 32 + quad * 8;
            if (BF16GATHER) {
                const short* pa = (s < 2) ? (xb + src0 * NDIM + kk)
                                          : (yb + dst0 * NDIM + (kk - 64));
                const short* pb = (s < 2) ? (xb + src1 * NDIM + kk)
                                          : (yb + dst1 * NDIM + (kk - 64));
                fa[s] = *reinterpret_cast<const short8*>(pa);
                fb[s] = *reinterpret_cast<const short8*>(pb);
            } else {
                fa[s] = make_afrag_f32((s < 2) ? (x + src0 * NDIM + kk)
                                               : (y + dst0 * NDIM + (kk - 64)));
                fb[s] = make_afrag_f32((s < 2) ? (x + src1 * NDIM + kk)
                                               : (y + dst1 * NDIM + (kk - 64)));
            }
        }
        // fold-step A: k=128 -> dist, k=129 -> 1.0 (quad 0 only; others zero)
        // bf16 pack: hi half = bf16(1.0) = 0x3F80, lo half = bf16(dist)
        short8 fa4, fb4;
        {
            union { int4v i; short8 s8; } ca, cb;
            int p0i, p1i;
            if (BF16GATHER) {
                p0i = (quad == 0) ? (0x3F800000 | (int)(unsigned short)dd0) : 0;
                p1i = (quad == 0) ? (0x3F800000 | (int)(unsigned short)dd1) : 0;
            } else {
                p0i = (quad == 0) ? pack2(fd0, 1.0f) : 0;
                p1i = (quad == 0) ? pack2(fd1, 1.0f) : 0;
            }
            ca.i = int4v{p0i, 0, 0, 0};
            cb.i = int4v{p1i, 0, 0, 0};
            fa4 = ca.s8; fb4 = cb.s8;
        }

        floatx4 accA[8], accB[8];
#pragma unroll
        for (int t = 0; t < 8; ++t) {
            accA[t] = floatx4{0.f, 0.f, 0.f, 0.f};
            accB[t] = floatx4{0.f, 0.f, 0.f, 0.f};
        }

        // B-fragments from LDS each iteration; zoff guard defeats LICM (keeps regs low).
        int zoff = 0;
        asm volatile("" : "+v"(zoff));
        const short* wr  = Wt + zoff + lm * KPAD + quad * 8;
        const short* wr5 = Wt + zoff + lm * KPAD + sel5;

#pragma unroll
        for (int t = 0; t < 8; ++t) {
            const short* base = wr + t * (16 * KPAD);
            const short8 bg0 = *reinterpret_cast<const short8*>(base);
            const short8 bg1 = *reinterpret_cast<const short8*>(base + 32);
            const short8 bg2 = *reinterpret_cast<const short8*>(base + 64);
            const short8 bg3 = *reinterpret_cast<const short8*>(base + 96);
            const short8 bg4 = *reinterpret_cast<const short8*>(wr5 + t * (16 * KPAD));
            accA[t] = __builtin_amdgcn_mfma_f32_16x16x32_bf16(fa[0], bg0, accA[t], 0, 0, 0);
            accB[t] = __builtin_amdgcn_mfma_f32_16x16x32_bf16(fb[0], bg0, accB[t], 0, 0, 0);
            accA[t] = __builtin_amdgcn_mfma_f32_16x16x32_bf16(fa[1], bg1, accA[t], 0, 0, 0);
            accB[t] = __builtin_amdgcn_mfma_f32_16x16x32_bf16(fb[1], bg1, accB[t], 0, 0, 0);
            accA[t] = __builtin_amdgcn_mfma_f32_16x16x32_bf16(fa[2], bg2, accA[t], 0, 0, 0);
            accB[t] = __builtin_amdgcn_mfma_f32_16x16x32_bf16(fb[2], bg2, accB[t], 0, 0, 0);
            accA[t] = __builtin_amdgcn_mfma_f32_16x16x32_bf16(fa[3], bg3, accA[t], 0, 0, 0);
            accB[t] = __builtin_amdgcn_mfma_f32_16x16x32_bf16(fb[3], bg3, accB[t], 0, 0, 0);
            accA[t] = __builtin_amdgcn_mfma_f32_16x16x32_bf16(fa4,  bg4, accA[t], 0, 0, 0);
            accB[t] = __builtin_amdgcn_mfma_f32_16x16x32_bf16(fb4,  bg4, accB[t], 0, 0, 0);
        }

        // ---- epilogue: relu, dot W2 (over n), quad-group reduce, +b2, relu ----
        // C/D layout: col n = lm + 16t, row m = quad*4 + reg
        float p0 = 0.f, p1 = 0.f, p2 = 0.f, p3 = 0.f;
        float q0 = 0.f, q1 = 0.f, q2 = 0.f, q3 = 0.f;
#pragma unroll
        for (int t = 0; t < 8; ++t) {
            p0 += fmaxf(accA[t][0], 0.f) * w2v[t];
            p1 += fmaxf(accA[t][1], 0.f) * w2v[t];
            p2 += fmaxf(accA[t][2], 0.f) * w2v[t];
            p3 += fmaxf(accA[t][3], 0.f) * w2v[t];
            q0 += fmaxf(accB[t][0], 0.f) * w2v[t];
            q1 += fmaxf(accB[t][1], 0.f) * w2v[t];
            q2 += fmaxf(accB[t][2], 0.f) * w2v[t];
            q3 += fmaxf(accB[t][3], 0.f) * w2v[t];
        }
#pragma unroll
        for (int off = 1; off < 16; off <<= 1) {
            p0 += __shfl_xor(p0, off, 64);
            p1 += __shfl_xor(p1, off, 64);
            p2 += __shfl_xor(p2, off, 64);
            p3 += __shfl_xor(p3, off, 64);
            q0 += __shfl_xor(q0, off, 64);
            q1 += __shfl_xor(q1, off, 64);
            q2 += __shfl_xor(q2, off, 64);
            q3 += __shfl_xor(q3, off, 64);
        }
        if (lm < 4) {
            const float vA = (lm == 0) ? p0 : (lm == 1) ? p1 : (lm == 2) ? p2 : p3;
            const float vB = (lm == 0) ? q0 : (lm == 1) ? q1 : (lm == 2) ? q2 : q3;
            const int eA = mb + quad * 4 + lm;
            const int eB = mb + 16 + quad * 4 + lm;
            if (eA < E) out[eA] = fmaxf(vA + b2s, 0.f);
            if (eB < E) out[eB] = fmaxf(vB + b2s, 0.f);
        }

        s0 = ns0; d0 = nd0; s1 = ns1; d1 = nd1;
        dd0 = ndd0; dd1 = ndd1;
    }
}

extern "C" void kernel_launch(void* const* d_in, const int* in_sizes, int n_in,
                              void* d_out, int out_size, void* d_ws, size_t ws_size,
                              hipStream_t stream)
{
    const float* x  = (const float*)d_in[0];
    const float* y  = (const float*)d_in[1];
    const int*   ei = (const int*)  d_in[2];
    const float* px = (const float*)d_in[3];
    const float* py = (const float*)d_in[4];
    const float* W1 = (const float*)d_in[5];
    const float* b1 = (const float*)d_in[6];
    const float* W2 = (const float*)d_in[7];
    const float* b2 = (const float*)d_in[8];
    float* out = (float*)d_out;
    const int E = in_sizes[2] / 2;
    const int nnode_elems = in_sizes[0];             // N_NODES * 64

    const size_t need = (size_t)nnode_elems * 2 * sizeof(short)
                      + (size_t)E * sizeof(short);
    if (ws_size >= need) {
        short* xb = (short*)d_ws;
        short* yb = xb + nnode_elems;
        short* db = yb + nnode_elems;
        cvt_kernel<<<dim3(1024), dim3(256), 0, stream>>>(
            x, y, ei, px, py, xb, yb, db, nnode_elems, E);
        // 1024 blocks x 512 thr = 4 blocks/CU, 32 waves/CU (VGPR<=64, LDS 4x34.8KB=139KB)
        edge_mlp_kernel<true><<<dim3(1024), dim3(512), 0, stream>>>(
            x, y, xb, yb, db, ei, px, py, W1, b1, W2, b2, out, E);
    } else {
        edge_mlp_kernel<false><<<dim3(1024), dim3(512), 0, stream>>>(
            x, y, nullptr, nullptr, nullptr, ei, px, py, W1, b1, W2, b2, out, E);
    }
}

// Round 7
// 170.287 us; speedup vs baseline: 3.6632x; 3.6632x over previous
//
#include <hip/hip_runtime.h>
#include <hip/hip_bf16.h>

// EdgeWeightFromDistance: out[e] = relu(relu([x[src], y[dst], dist] @ W1 + b1) @ W2 + b2)
// E = 1e6, NODE_DIM = 64, HIDDEN = 128.
// R7: R6's 512-thr/8-waves config spilled (unified reg budget 64 < acc 64 + arch) ->
//     reverted to R5 (256 thr, lb(256,4), 16 waves/CU = structural ceiling for M=32).
//     New wall model: TA lane-address throughput (~1 addr/cyc/CU; ~850 addrs per
//     32-edge wave-iter ~= measured 35 cyc/edge). This round cuts redundant addrs:
//     idx prefetch 4 broadcast loads (256 addrs) -> 1 lane-distinct load (64) + 4 shfl;
//     dist 2 loads -> 1 masked 32-lane load + 2 shfl.

constexpr int NDIM  = 64;
constexpr int HID   = 128;
constexpr int KPAD  = 136;   // bf16 elems per Wt row: 128 data + w1r + b1 + 6 zeros; 272 B

typedef __attribute__((ext_vector_type(8))) short  short8;
typedef __attribute__((ext_vector_type(4))) int    int4v;
typedef __attribute__((ext_vector_type(4))) float  floatx4;

__device__ __forceinline__ short f2bf(float f) {
    union { __hip_bfloat16 h; short s; } cv;
    cv.h = __float2bfloat16(f);
    return cv.s;
}

__device__ __forceinline__ int pack2(float a, float b) {
    union { __hip_bfloat162 h; int u; } cv;
    cv.h = __float22bfloat162_rn(float2{a, b});
    return cv.u;
}

__device__ __forceinline__ short8 make_afrag_f32(const float* rp) {
    const floatx4 f0 = *reinterpret_cast<const floatx4*>(rp);
    const floatx4 f1 = *reinterpret_cast<const floatx4*>(rp + 4);
    union { int4v i; short8 s8; } cv;
    cv.i.x = pack2(f0.x, f0.y);
    cv.i.y = pack2(f0.z, f0.w);
    cv.i.z = pack2(f1.x, f1.y);
    cv.i.w = pack2(f1.z, f1.w);
    return cv.s8;
}

// ---- streaming fp32 -> bf16 convert of x,y + per-edge bf16 dist into workspace ----
__global__ __launch_bounds__(256) void cvt_kernel(
    const float* __restrict__ xin, const float* __restrict__ yin,
    const int*  __restrict__ ei,  const float* __restrict__ px,
    const float* __restrict__ py,
    short* __restrict__ xb, short* __restrict__ yb, short* __restrict__ db,
    int nfl, int E)
{
    const int stride = gridDim.x * blockDim.x;
    const int gid = blockIdx.x * blockDim.x + threadIdx.x;
    const int n8 = nfl >> 3;
    for (int i = gid; i < n8; i += stride) {
        {
            const floatx4 f0 = *reinterpret_cast<const floatx4*>(xin + i * 8);
            const floatx4 f1 = *reinterpret_cast<const floatx4*>(xin + i * 8 + 4);
            union { int4v v; short8 s; } c;
            c.v.x = pack2(f0.x, f0.y); c.v.y = pack2(f0.z, f0.w);
            c.v.z = pack2(f1.x, f1.y); c.v.w = pack2(f1.z, f1.w);
            *reinterpret_cast<short8*>(xb + i * 8) = c.s;
        }
        {
            const floatx4 f0 = *reinterpret_cast<const floatx4*>(yin + i * 8);
            const floatx4 f1 = *reinterpret_cast<const floatx4*>(yin + i * 8 + 4);
            union { int4v v; short8 s; } c;
            c.v.x = pack2(f0.x, f0.y); c.v.y = pack2(f0.z, f0.w);
            c.v.z = pack2(f1.x, f1.y); c.v.w = pack2(f1.z, f1.w);
            *reinterpret_cast<short8*>(yb + i * 8) = c.s;
        }
    }
    // per-edge distance (pos arrays are 2.4 MB total -> L2-resident gathers)
    for (int e = gid; e < E; e += stride) {
        const int s = ei[e];
        const int d = ei[E + e];
        const float dx = px[s * 3 + 0] - py[d * 3 + 0];
        const float dy = px[s * 3 + 1] - py[d * 3 + 1];
        const float dz = px[s * 3 + 2] - py[d * 3 + 2];
        db[e] = f2bf(sqrtf(dx * dx + dy * dy + dz * dz));
    }
}

template <bool BF16GATHER>
__global__ __launch_bounds__(256, 4) void edge_mlp_kernel(
    const float* __restrict__ x, const float* __restrict__ y,
    const short* __restrict__ xb, const short* __restrict__ yb,
    const short* __restrict__ db,
    const int*  __restrict__ ei, const float* __restrict__ px,
    const float* __restrict__ py, const float* __restrict__ W1,
    const float* __restrict__ b1, const float* __restrict__ W2,
    const float* __restrict__ b2, float* __restrict__ out, int E)
{
    __shared__ __align__(16) short Wt[HID * KPAD];   // W1^T [n][k] in bf16 (+ fold rows)

    const int tid = threadIdx.x;

    // ---- stage W1[0:128][0:128] transposed into LDS ----
    for (int base = 0; base < HID * HID; base += 256 * 8) {
        float f[8];
#pragma unroll
        for (int u = 0; u < 8; ++u) f[u] = W1[base + u * 256 + tid];
#pragma unroll
        for (int u = 0; u < 8; ++u) {
            int i = base + u * 256 + tid;
            Wt[(i & 127) * KPAD + (i >> 7)] = f2bf(f[u]);
        }
    }
    // fold rows: k=128 -> w1r (dist coeff), k=129 -> b1, k=130..135 -> 0
    if (tid < HID) {
        const int n = tid;
        Wt[n * KPAD + 128] = f2bf(W1[128 * HID + n]);
        Wt[n * KPAD + 129] = f2bf(b1[n]);
#pragma unroll
        for (int j = 130; j < 136; ++j) Wt[n * KPAD + j] = 0;
    }
    __syncthreads();

    const int lane = tid & 63;
    const int wave = tid >> 6;
    const int quad = lane >> 4;
    const int lm   = lane & 15;   // A-frag row m; B-frag/C-D col n (within tile)

    float w2v[8];
#pragma unroll
    for (int t = 0; t < 8; ++t) w2v[t] = W2[t * 16 + lm];
    const float b2s = b2[0];

    const int* __restrict__ srcp = ei;
    const int* __restrict__ dstp = ei + E;

    const int sel5 = (quad == 0) ? 128 : 0;   // fold-step k-offset

    const int ntiles = (E + 127) / 128;       // 128 edges per block-iter, 32 per wave
    int tile = blockIdx.x;
    if (tile >= ntiles) return;

    // ---- prefetch first tile's indices (+ dist) via one lane-distinct load + shfl ----
    // lanes 0..31 read srcp[mb..mb+31], lanes 32..63 read dstp[mb..mb+31]:
    //   src0 = lane lm, src1 = lane 16+lm, dst0 = lane 32+lm, dst1 = lane 48+lm.
    int s0, d0, s1, d1;
    int dd0 = 0, dd1 = 0;
    float fd0 = 0.f, fd1 = 0.f;   // fallback-path dist
    {
        const int mb = tile * 128 + wave * 32;
        const int li = min(mb + (lane & 31), E - 1);
        const int vidx = (lane < 32) ? srcp[li] : dstp[li];
        s0 = __shfl(vidx, lm, 64);
        s1 = __shfl(vidx, 16 + lm, 64);
        d0 = __shfl(vidx, 32 + lm, 64);
        d1 = __shfl(vidx, 48 + lm, 64);
        if (BF16GATHER) {
            int vd = 0;
            if (lane < 32) vd = (int)(unsigned short)db[li];
            dd0 = __shfl(vd, lm, 64);
            dd1 = __shfl(vd, 16 + lm, 64);
        }
    }

    for (; tile < ntiles; tile += gridDim.x) {
        // ---- kick off next tile's idx/dist loads (no deps on current work) ----
        const int nt = tile + gridDim.x;
        const int qt = (nt < ntiles) ? nt : tile;
        const int qmb = qt * 128 + wave * 32;
        const int qli = min(qmb + (lane & 31), E - 1);
        const int nvidx = (lane < 32) ? srcp[qli] : dstp[qli];
        int nvd = 0;
        if (BF16GATHER) {
            if (lane < 32) nvd = (int)(unsigned short)db[qli];
        }

        const int mb = tile * 128 + wave * 32;
        const int src0 = s0, dst0 = d0, src1 = s1, dst1 = d1;

        if (!BF16GATHER) {
            const float dx0 = px[src0 * 3 + 0] - py[dst0 * 3 + 0];
            const float dy0 = px[src0 * 3 + 1] - py[dst0 * 3 + 1];
            const float dz0 = px[src0 * 3 + 2] - py[dst0 * 3 + 2];
            fd0 = sqrtf(dx0 * dx0 + dy0 * dy0 + dz0 * dz0);
            const float dx1 = px[src1 * 3 + 0] - py[dst1 * 3 + 0];
            const float dy1 = px[src1 * 3 + 1] - py[dst1 * 3 + 1];
            const float dz1 = px[src1 * 3 + 2] - py[dst1 * 3 + 2];
            fd1 = sqrtf(dx1 * dx1 + dy1 * dy1 + dz1 * dz1);
        }

        // ---- A fragments: row m, k = s*32 + quad*8 + j ----
        short8 fa[4], fb[4];
#pragma unroll
        for (int s = 0; s < 4; ++s) {
            const int kk = s * 32 + quad * 8;
            if (BF16GATHER) {
                const short* pa = (s < 2) ? (xb + src0 * NDIM + kk)
                                          : (yb + dst0 * NDIM + (kk - 64));
                const short* pb = (s < 2) ? (xb + src1 * NDIM + kk)
                                          : (yb + dst1 * NDIM + (kk - 64));
                fa[s] = *reinterpret_cast<const short8*>(pa);
                fb[s] = *reinterpret_cast<const short8*>(pb);
            } else {
                fa[s] = make_afrag_f32((s < 2) ? (x + src0 * NDIM + kk)
                                               : (y + dst0 * NDIM + (kk - 64)));
                fb[s] = make_afrag_f32((s < 2) ? (x + src1 * NDIM + kk)
                                               : (y + dst1 * NDIM + (kk - 64)));
            }
        }
        // fold-step A: k=128 -> dist, k=129 -> 1.0 (quad 0 only; others zero)
        // bf16 pack: hi half = bf16(1.0) = 0x3F80, lo half = bf16(dist)
        short8 fa4, fb4;
        {
            union { int4v i; short8 s8; } ca, cb;
            int p0i, p1i;
            if (BF16GATHER) {
                p0i = (quad == 0) ? (0x3F800000 | dd0) : 0;
                p1i = (quad == 0) ? (0x3F800000 | dd1) : 0;
            } else {
                p0i = (quad == 0) ? pack2(fd0, 1.0f) : 0;
                p1i = (quad == 0) ? pack2(fd1, 1.0f) : 0;
            }
            ca.i = int4v{p0i, 0, 0, 0};
            cb.i = int4v{p1i, 0, 0, 0};
            fa4 = ca.s8; fb4 = cb.s8;
        }

        floatx4 accA[8], accB[8];
#pragma unroll
        for (int t = 0; t < 8; ++t) {
            accA[t] = floatx4{0.f, 0.f, 0.f, 0.f};
            accB[t] = floatx4{0.f, 0.f, 0.f, 0.f};
        }

        // B-fragments from LDS each iteration; zoff guard defeats LICM (keeps regs low).
        int zoff = 0;
        asm volatile("" : "+v"(zoff));
        const short* wr  = Wt + zoff + lm * KPAD + quad * 8;
        const short* wr5 = Wt + zoff + lm * KPAD + sel5;

#pragma unroll
        for (int t = 0; t < 8; ++t) {
            const short* base = wr + t * (16 * KPAD);
            const short8 bg0 = *reinterpret_cast<const short8*>(base);
            const short8 bg1 = *reinterpret_cast<const short8*>(base + 32);
            const short8 bg2 = *reinterpret_cast<const short8*>(base + 64);
            const short8 bg3 = *reinterpret_cast<const short8*>(base + 96);
            const short8 bg4 = *reinterpret_cast<const short8*>(wr5 + t * (16 * KPAD));
            accA[t] = __builtin_amdgcn_mfma_f32_16x16x32_bf16(fa[0], bg0, accA[t], 0, 0, 0);
            accB[t] = __builtin_amdgcn_mfma_f32_16x16x32_bf16(fb[0], bg0, accB[t], 0, 0, 0);
            accA[t] = __builtin_amdgcn_mfma_f32_16x16x32_bf16(fa[1], bg1, accA[t], 0, 0, 0);
            accB[t] = __builtin_amdgcn_mfma_f32_16x16x32_bf16(fb[1], bg1, accB[t], 0, 0, 0);
            accA[t] = __builtin_amdgcn_mfma_f32_16x16x32_bf16(fa[2], bg2, accA[t], 0, 0, 0);
            accB[t] = __builtin_amdgcn_mfma_f32_16x16x32_bf16(fb[2], bg2, accB[t], 0, 0, 0);
            accA[t] = __builtin_amdgcn_mfma_f32_16x16x32_bf16(fa[3], bg3, accA[t], 0, 0, 0);
            accB[t] = __builtin_amdgcn_mfma_f32_16x16x32_bf16(fb[3], bg3, accB[t], 0, 0, 0);
            accA[t] = __builtin_amdgcn_mfma_f32_16x16x32_bf16(fa4,  bg4, accA[t], 0, 0, 0);
            accB[t] = __builtin_amdgcn_mfma_f32_16x16x32_bf16(fb4,  bg4, accB[t], 0, 0, 0);
        }

        // ---- epilogue: relu, dot W2 (over n), quad-group reduce, +b2, relu ----
        // C/D layout: col n = lm + 16t, row m = quad*4 + reg
        float p0 = 0.f, p1 = 0.f, p2 = 0.f, p3 = 0.f;
        float q0 = 0.f, q1 = 0.f, q2 = 0.f, q3 = 0.f;
#pragma unroll
        for (int t = 0; t < 8; ++t) {
            p0 += fmaxf(accA[t][0], 0.f) * w2v[t];
            p1 += fmaxf(accA[t][1], 0.f) * w2v[t];
            p2 += fmaxf(accA[t][2], 0.f) * w2v[t];
            p3 += fmaxf(accA[t][3], 0.f) * w2v[t];
            q0 += fmaxf(accB[t][0], 0.f) * w2v[t];
            q1 += fmaxf(accB[t][1], 0.f) * w2v[t];
            q2 += fmaxf(accB[t][2], 0.f) * w2v[t];
            q3 += fmaxf(accB[t][3], 0.f) * w2v[t];
        }
#pragma unroll
        for (int off = 1; off < 16; off <<= 1) {
            p0 += __shfl_xor(p0, off, 64);
            p1 += __shfl_xor(p1, off, 64);
            p2 += __shfl_xor(p2, off, 64);
            p3 += __shfl_xor(p3, off, 64);
            q0 += __shfl_xor(q0, off, 64);
            q1 += __shfl_xor(q1, off, 64);
            q2 += __shfl_xor(q2, off, 64);
            q3 += __shfl_xor(q3, off, 64);
        }
        if (lm < 4) {
            const float vA = (lm == 0) ? p0 : (lm == 1) ? p1 : (lm == 2) ? p2 : p3;
            const float vB = (lm == 0) ? q0 : (lm == 1) ? q1 : (lm == 2) ? q2 : q3;
            const int eA = mb + quad * 4 + lm;
            const int eB = mb + 16 + quad * 4 + lm;
            if (eA < E) out[eA] = fmaxf(vA + b2s, 0.f);
            if (eB < E) out[eB] = fmaxf(vB + b2s, 0.f);
        }

        // distribute prefetched idx/dist for the next iteration
        s0 = __shfl(nvidx, lm, 64);
        s1 = __shfl(nvidx, 16 + lm, 64);
        d0 = __shfl(nvidx, 32 + lm, 64);
        d1 = __shfl(nvidx, 48 + lm, 64);
        if (BF16GATHER) {
            dd0 = __shfl(nvd, lm, 64);
            dd1 = __shfl(nvd, 16 + lm, 64);
        }
    }
}

extern "C" void kernel_launch(void* const* d_in, const int* in_sizes, int n_in,
                              void* d_out, int out_size, void* d_ws, size_t ws_size,
                              hipStream_t stream)
{
    const float* x  = (const float*)d_in[0];
    const float* y  = (const float*)d_in[1];
    const int*   ei = (const int*)  d_in[2];
    const float* px = (const float*)d_in[3];
    const float* py = (const float*)d_in[4];
    const float* W1 = (const float*)d_in[5];
    const float* b1 = (const float*)d_in[6];
    const float* W2 = (const float*)d_in[7];
    const float* b2 = (const float*)d_in[8];
    float* out = (float*)d_out;
    const int E = in_sizes[2] / 2;
    const int nnode_elems = in_sizes[0];             // N_NODES * 64

    const size_t need = (size_t)nnode_elems * 2 * sizeof(short)
                      + (size_t)E * sizeof(short);
    if (ws_size >= need) {
        short* xb = (short*)d_ws;
        short* yb = xb + nnode_elems;
        short* db = yb + nnode_elems;
        cvt_kernel<<<dim3(1024), dim3(256), 0, stream>>>(
            x, y, ei, px, py, xb, yb, db, nnode_elems, E);
        // 1024 blocks x 256 thr, lb(256,4): 4 blocks/CU, 16 waves/CU (M=32 reg ceiling)
        edge_mlp_kernel<true><<<dim3(1024), dim3(256), 0, stream>>>(
            x, y, xb, yb, db, ei, px, py, W1, b1, W2, b2, out, E);
    } else {
        edge_mlp_kernel<false><<<dim3(1024), dim3(256), 0, stream>>>(
            x, y, nullptr, nullptr, nullptr, ei, px, py, W1, b1, W2, b2, out, E);
    }
}

// Round 8
// 163.527 us; speedup vs baseline: 3.8146x; 1.0413x over previous
//
#include <hip/hip_runtime.h>
#include <hip/hip_bf16.h>

// EdgeWeightFromDistance: out[e] = relu(relu([x[src], y[dst], dist] @ W1 + b1) @ W2 + b2)
// E = 1e6, NODE_DIM = 64, HIDDEN = 128.
// R8: per-pipe accounting says LDS is the top pipe (~78%): 480cyc b128 B-stream
//     (structural) + ~200cyc shuffles + 178cyc conflicts per wave-iter.
//  - R7's idx-shuffle scheme regressed (broadcast loads are near-free) -> reverted to R5.
//  - Epilogue 16-lane butterfly moved off the LDS pipe: DPP row_shr adds (VALU);
//    row sums land in lane 15 of each DPP row -> float4 stores (32 scalar -> 8 vec).

constexpr int NDIM  = 64;
constexpr int HID   = 128;
constexpr int KPAD  = 136;   // bf16 elems per Wt row: 128 data + w1r + b1 + 6 zeros; 272 B

typedef __attribute__((ext_vector_type(8))) short  short8;
typedef __attribute__((ext_vector_type(4))) int    int4v;
typedef __attribute__((ext_vector_type(4))) float  floatx4;

__device__ __forceinline__ short f2bf(float f) {
    union { __hip_bfloat16 h; short s; } cv;
    cv.h = __float2bfloat16(f);
    return cv.s;
}

__device__ __forceinline__ int pack2(float a, float b) {
    union { __hip_bfloat162 h; int u; } cv;
    cv.h = __float22bfloat162_rn(float2{a, b});
    return cv.u;
}

__device__ __forceinline__ short8 make_afrag_f32(const float* rp) {
    const floatx4 f0 = *reinterpret_cast<const floatx4*>(rp);
    const floatx4 f1 = *reinterpret_cast<const floatx4*>(rp + 4);
    union { int4v i; short8 s8; } cv;
    cv.i.x = pack2(f0.x, f0.y);
    cv.i.y = pack2(f0.z, f0.w);
    cv.i.z = pack2(f1.x, f1.y);
    cv.i.w = pack2(f1.z, f1.w);
    return cv.s8;
}

// DPP row (16-lane) prefix-sum step on the VALU pipe; full sum ends in lane 15 of row.
template <int CTRL>
__device__ __forceinline__ float dpp_row_add(float v) {
    union { float f; int i; } a, b;
    a.f = v;
    b.i = __builtin_amdgcn_update_dpp(0, a.i, CTRL, 0xF, 0xF, true);
    return v + b.f;
}
__device__ __forceinline__ float row_reduce16(float v) {
    v = dpp_row_add<0x111>(v);   // row_shr:1
    v = dpp_row_add<0x112>(v);   // row_shr:2
    v = dpp_row_add<0x114>(v);   // row_shr:4
    v = dpp_row_add<0x118>(v);   // row_shr:8
    return v;                    // lane lm==15 holds the 16-lane sum
}

// ---- streaming fp32 -> bf16 convert of x,y + per-edge bf16 dist into workspace ----
__global__ __launch_bounds__(256) void cvt_kernel(
    const float* __restrict__ xin, const float* __restrict__ yin,
    const int*  __restrict__ ei,  const float* __restrict__ px,
    const float* __restrict__ py,
    short* __restrict__ xb, short* __restrict__ yb, short* __restrict__ db,
    int nfl, int E)
{
    const int stride = gridDim.x * blockDim.x;
    const int gid = blockIdx.x * blockDim.x + threadIdx.x;
    const int n8 = nfl >> 3;
    for (int i = gid; i < n8; i += stride) {
        {
            const floatx4 f0 = *reinterpret_cast<const floatx4*>(xin + i * 8);
            const floatx4 f1 = *reinterpret_cast<const floatx4*>(xin + i * 8 + 4);
            union { int4v v; short8 s; } c;
            c.v.x = pack2(f0.x, f0.y); c.v.y = pack2(f0.z, f0.w);
            c.v.z = pack2(f1.x, f1.y); c.v.w = pack2(f1.z, f1.w);
            *reinterpret_cast<short8*>(xb + i * 8) = c.s;
        }
        {
            const floatx4 f0 = *reinterpret_cast<const floatx4*>(yin + i * 8);
            const floatx4 f1 = *reinterpret_cast<const floatx4*>(yin + i * 8 + 4);
            union { int4v v; short8 s; } c;
            c.v.x = pack2(f0.x, f0.y); c.v.y = pack2(f0.z, f0.w);
            c.v.z = pack2(f1.x, f1.y); c.v.w = pack2(f1.z, f1.w);
            *reinterpret_cast<short8*>(yb + i * 8) = c.s;
        }
    }
    // per-edge distance (pos arrays are 2.4 MB total -> L2-resident gathers)
    for (int e = gid; e < E; e += stride) {
        const int s = ei[e];
        const int d = ei[E + e];
        const float dx = px[s * 3 + 0] - py[d * 3 + 0];
        const float dy = px[s * 3 + 1] - py[d * 3 + 1];
        const float dz = px[s * 3 + 2] - py[d * 3 + 2];
        db[e] = f2bf(sqrtf(dx * dx + dy * dy + dz * dz));
    }
}

template <bool BF16GATHER>
__global__ __launch_bounds__(256, 4) void edge_mlp_kernel(
    const float* __restrict__ x, const float* __restrict__ y,
    const short* __restrict__ xb, const short* __restrict__ yb,
    const short* __restrict__ db,
    const int*  __restrict__ ei, const float* __restrict__ px,
    const float* __restrict__ py, const float* __restrict__ W1,
    const float* __restrict__ b1, const float* __restrict__ W2,
    const float* __restrict__ b2, float* __restrict__ out, int E)
{
    __shared__ __align__(16) short Wt[HID * KPAD];   // W1^T [n][k] in bf16 (+ fold rows)

    const int tid = threadIdx.x;

    // ---- stage W1[0:128][0:128] transposed into LDS ----
    for (int base = 0; base < HID * HID; base += 256 * 8) {
        float f[8];
#pragma unroll
        for (int u = 0; u < 8; ++u) f[u] = W1[base + u * 256 + tid];
#pragma unroll
        for (int u = 0; u < 8; ++u) {
            int i = base + u * 256 + tid;
            Wt[(i & 127) * KPAD + (i >> 7)] = f2bf(f[u]);
        }
    }
    // fold rows: k=128 -> w1r (dist coeff), k=129 -> b1, k=130..135 -> 0
    if (tid < HID) {
        const int n = tid;
        Wt[n * KPAD + 128] = f2bf(W1[128 * HID + n]);
        Wt[n * KPAD + 129] = f2bf(b1[n]);
#pragma unroll
        for (int j = 130; j < 136; ++j) Wt[n * KPAD + j] = 0;
    }
    __syncthreads();

    const int lane = tid & 63;
    const int wave = tid >> 6;
    const int quad = lane >> 4;
    const int lm   = lane & 15;   // A-frag row m; B-frag/C-D col n (within tile)

    float w2v[8];
#pragma unroll
    for (int t = 0; t < 8; ++t) w2v[t] = W2[t * 16 + lm];
    const float b2s = b2[0];

    const int* __restrict__ srcp = ei;
    const int* __restrict__ dstp = ei + E;

    const int sel5 = (quad == 0) ? 128 : 0;   // fold-step k-offset

    const int ntiles = (E + 127) / 128;       // 128 edges per block-iter, 32 per wave
    int tile = blockIdx.x;
    if (tile >= ntiles) return;

    // ---- prefetch first tile's indices (+ dist for quad 0) ----
    int s0, d0, s1, d1;
    short dd0 = 0, dd1 = 0;
    float fd0 = 0.f, fd1 = 0.f;   // fallback-path dist
    {
        const int mb = tile * 128 + wave * 32;
        const int m0 = min(mb + lm, E - 1);
        const int m1 = min(mb + 16 + lm, E - 1);
        s0 = srcp[m0]; d0 = dstp[m0]; s1 = srcp[m1]; d1 = dstp[m1];
        if (BF16GATHER) {
            if (quad == 0) { dd0 = db[m0]; dd1 = db[m1]; }
        }
    }

    for (; tile < ntiles; tile += gridDim.x) {
        // ---- kick off next tile's idx/dist loads (no deps on current work) ----
        const int nt = tile + gridDim.x;
        const int qt = (nt < ntiles) ? nt : tile;
        const int qmb = qt * 128 + wave * 32;
        const int qm0 = min(qmb + lm, E - 1);
        const int qm1 = min(qmb + 16 + lm, E - 1);
        const int ns0 = srcp[qm0], nd0 = dstp[qm0];
        const int ns1 = srcp[qm1], nd1 = dstp[qm1];
        short ndd0 = 0, ndd1 = 0;
        if (BF16GATHER) {
            if (quad == 0) { ndd0 = db[qm0]; ndd1 = db[qm1]; }
        }

        const int mb = tile * 128 + wave * 32;
        const int src0 = s0, dst0 = d0, src1 = s1, dst1 = d1;

        if (!BF16GATHER) {
            const float dx0 = px[src0 * 3 + 0] - py[dst0 * 3 + 0];
            const float dy0 = px[src0 * 3 + 1] - py[dst0 * 3 + 1];
            const float dz0 = px[src0 * 3 + 2] - py[dst0 * 3 + 2];
            fd0 = sqrtf(dx0 * dx0 + dy0 * dy0 + dz0 * dz0);
            const float dx1 = px[src1 * 3 + 0] - py[dst1 * 3 + 0];
            const float dy1 = px[src1 * 3 + 1] - py[dst1 * 3 + 1];
            const float dz1 = px[src1 * 3 + 2] - py[dst1 * 3 + 2];
            fd1 = sqrtf(dx1 * dx1 + dy1 * dy1 + dz1 * dz1);
        }

        // ---- A fragments: row m, k = s*32 + quad*8 + j ----
        short8 fa[4], fb[4];
#pragma unroll
        for (int s = 0; s < 4; ++s) {
            const int kk = s * 32 + quad * 8;
            if (BF16GATHER) {
                const short* pa = (s < 2) ? (xb + src0 * NDIM + kk)
                                          : (yb + dst0 * NDIM + (kk - 64));
                const short* pb = (s < 2) ? (xb + src1 * NDIM + kk)
                                          : (yb + dst1 * NDIM + (kk - 64));
                fa[s] = *reinterpret_cast<const short8*>(pa);
                fb[s] = *reinterpret_cast<const short8*>(pb);
            } else {
                fa[s] = make_afrag_f32((s < 2) ? (x + src0 * NDIM + kk)
                                               : (y + dst0 * NDIM + (kk - 64)));
                fb[s] = make_afrag_f32((s < 2) ? (x + src1 * NDIM + kk)
                                               : (y + dst1 * NDIM + (kk - 64)));
            }
        }
        // fold-step A: k=128 -> dist, k=129 -> 1.0 (quad 0 only; others zero)
        // bf16 pack: hi half = bf16(1.0) = 0x3F80, lo half = bf16(dist)
        short8 fa4, fb4;
        {
            union { int4v i; short8 s8; } ca, cb;
            int p0i, p1i;
            if (BF16GATHER) {
                p0i = (quad == 0) ? (0x3F800000 | (int)(unsigned short)dd0) : 0;
                p1i = (quad == 0) ? (0x3F800000 | (int)(unsigned short)dd1) : 0;
            } else {
                p0i = (quad == 0) ? pack2(fd0, 1.0f) : 0;
                p1i = (quad == 0) ? pack2(fd1, 1.0f) : 0;
            }
            ca.i = int4v{p0i, 0, 0, 0};
            cb.i = int4v{p1i, 0, 0, 0};
            fa4 = ca.s8; fb4 = cb.s8;
        }

        floatx4 accA[8], accB[8];
#pragma unroll
        for (int t = 0; t < 8; ++t) {
            accA[t] = floatx4{0.f, 0.f, 0.f, 0.f};
            accB[t] = floatx4{0.f, 0.f, 0.f, 0.f};
        }

        // B-fragments from LDS each iteration; zoff guard defeats LICM (keeps regs low).
        int zoff = 0;
        asm volatile("" : "+v"(zoff));
        const short* wr  = Wt + zoff + lm * KPAD + quad * 8;
        const short* wr5 = Wt + zoff + lm * KPAD + sel5;

#pragma unroll
        for (int t = 0; t < 8; ++t) {
            const short* base = wr + t * (16 * KPAD);
            const short8 bg0 = *reinterpret_cast<const short8*>(base);
            const short8 bg1 = *reinterpret_cast<const short8*>(base + 32);
            const short8 bg2 = *reinterpret_cast<const short8*>(base + 64);
            const short8 bg3 = *reinterpret_cast<const short8*>(base + 96);
            const short8 bg4 = *reinterpret_cast<const short8*>(wr5 + t * (16 * KPAD));
            accA[t] = __builtin_amdgcn_mfma_f32_16x16x32_bf16(fa[0], bg0, accA[t], 0, 0, 0);
            accB[t] = __builtin_amdgcn_mfma_f32_16x16x32_bf16(fb[0], bg0, accB[t], 0, 0, 0);
            accA[t] = __builtin_amdgcn_mfma_f32_16x16x32_bf16(fa[1], bg1, accA[t], 0, 0, 0);
            accB[t] = __builtin_amdgcn_mfma_f32_16x16x32_bf16(fb[1], bg1, accB[t], 0, 0, 0);
            accA[t] = __builtin_amdgcn_mfma_f32_16x16x32_bf16(fa[2], bg2, accA[t], 0, 0, 0);
            accB[t] = __builtin_amdgcn_mfma_f32_16x16x32_bf16(fb[2], bg2, accB[t], 0, 0, 0);
            accA[t] = __builtin_amdgcn_mfma_f32_16x16x32_bf16(fa[3], bg3, accA[t], 0, 0, 0);
            accB[t] = __builtin_amdgcn_mfma_f32_16x16x32_bf16(fb[3], bg3, accB[t], 0, 0, 0);
            accA[t] = __builtin_amdgcn_mfma_f32_16x16x32_bf16(fa4,  bg4, accA[t], 0, 0, 0);
            accB[t] = __builtin_amdgcn_mfma_f32_16x16x32_bf16(fb4,  bg4, accB[t], 0, 0, 0);
        }

        // ---- epilogue: relu, dot W2 (over n), DPP row-reduce, +b2, relu ----
        // C/D layout: col n = lm + 16t, row m = quad*4 + reg.
        // Reduction over the 16 lm lanes == one DPP row; sum lands in lane lm==15.
        float p0 = 0.f, p1 = 0.f, p2 = 0.f, p3 = 0.f;
        float q0 = 0.f, q1 = 0.f, q2 = 0.f, q3 = 0.f;
#pragma unroll
        for (int t = 0; t < 8; ++t) {
            p0 += fmaxf(accA[t][0], 0.f) * w2v[t];
            p1 += fmaxf(accA[t][1], 0.f) * w2v[t];
            p2 += fmaxf(accA[t][2], 0.f) * w2v[t];
            p3 += fmaxf(accA[t][3], 0.f) * w2v[t];
            q0 += fmaxf(accB[t][0], 0.f) * w2v[t];
            q1 += fmaxf(accB[t][1], 0.f) * w2v[t];
            q2 += fmaxf(accB[t][2], 0.f) * w2v[t];
            q3 += fmaxf(accB[t][3], 0.f) * w2v[t];
        }
        p0 = row_reduce16(p0); p1 = row_reduce16(p1);
        p2 = row_reduce16(p2); p3 = row_reduce16(p3);
        q0 = row_reduce16(q0); q1 = row_reduce16(q1);
        q2 = row_reduce16(q2); q3 = row_reduce16(q3);

        if (lm == 15) {
            const int eA = mb + quad * 4;        // rows quad*4 + {0,1,2,3}
            const int eB = mb + 16 + quad * 4;
            if (eA < E) {                        // E%16==0: eA<E => eA+3<E
                floatx4 oA;
                oA.x = fmaxf(p0 + b2s, 0.f);
                oA.y = fmaxf(p1 + b2s, 0.f);
                oA.z = fmaxf(p2 + b2s, 0.f);
                oA.w = fmaxf(p3 + b2s, 0.f);
                *reinterpret_cast<floatx4*>(out + eA) = oA;
            }
            if (eB < E) {
                floatx4 oB;
                oB.x = fmaxf(q0 + b2s, 0.f);
                oB.y = fmaxf(q1 + b2s, 0.f);
                oB.z = fmaxf(q2 + b2s, 0.f);
                oB.w = fmaxf(q3 + b2s, 0.f);
                *reinterpret_cast<floatx4*>(out + eB) = oB;
            }
        }

        s0 = ns0; d0 = nd0; s1 = ns1; d1 = nd1;
        dd0 = ndd0; dd1 = ndd1;
    }
}

extern "C" void kernel_launch(void* const* d_in, const int* in_sizes, int n_in,
                              void* d_out, int out_size, void* d_ws, size_t ws_size,
                              hipStream_t stream)
{
    const float* x  = (const float*)d_in[0];
    const float* y  = (const float*)d_in[1];
    const int*   ei = (const int*)  d_in[2];
    const float* px = (const float*)d_in[3];
    const float* py = (const float*)d_in[4];
    const float* W1 = (const float*)d_in[5];
    const float* b1 = (const float*)d_in[6];
    const float* W2 = (const float*)d_in[7];
    const float* b2 = (const float*)d_in[8];
    float* out = (float*)d_out;
    const int E = in_sizes[2] / 2;
    const int nnode_elems = in_sizes[0];             // N_NODES * 64

    const size_t need = (size_t)nnode_elems * 2 * sizeof(short)
                      + (size_t)E * sizeof(short);
    if (ws_size >= need) {
        short* xb = (short*)d_ws;
        short* yb = xb + nnode_elems;
        short* db = yb + nnode_elems;
        cvt_kernel<<<dim3(1024), dim3(256), 0, stream>>>(
            x, y, ei, px, py, xb, yb, db, nnode_elems, E);
        // 1024 blocks x 256 thr, lb(256,4): 4 blocks/CU, 16 waves/CU (M=32 reg ceiling)
        edge_mlp_kernel<true><<<dim3(1024), dim3(256), 0, stream>>>(
            x, y, xb, yb, db, ei, px, py, W1, b1, W2, b2, out, E);
    } else {
        edge_mlp_kernel<false><<<dim3(1024), dim3(256), 0, stream>>>(
            x, y, nullptr, nullptr, nullptr, ei, px, py, W1, b1, W2, b2, out, E);
    }
}